// Round 4
// baseline (130.255 us; speedup 1.0000x reference)
//
#include <hip/hip_runtime.h>
#include <cmath>

#define NKEY 3072
#define KSEL 100
#define PCHUNK 100   // preds per k_maxiou block; grid.y = 6400/PCHUNK = 64

static __device__ __forceinline__ float sigf(float v) {
    return 1.0f / (1.0f + expf(-v));
}

// Block (256 threads) sum-reduction in double. Valid result on thread 0.
// Leading barrier makes back-to-back calls safe.
static __device__ double block_reduce_sum(double v) {
    __shared__ double sh[4];
    __syncthreads();
    for (int off = 32; off > 0; off >>= 1) v += __shfl_down(v, off, 64);
    int lane = threadIdx.x & 63, wid = threadIdx.x >> 6;
    if (lane == 0) sh[wid] = v;
    __syncthreads();
    v = (threadIdx.x < 4) ? sh[threadIdx.x] : 0.0;
    if (wid == 0) {
        v += __shfl_down(v, 2, 64);
        v += __shfl_down(v, 1, 64);
    }
    return v;
}

// ---------------------------------------------------------------------------
// k_topk: ONE WAVE (64 threads) per batch, 64 blocks. Single-wave workgroup
// => every __syncthreads is trivially satisfied (no inter-wave serialization);
// the radix select runs as wave-synchronous straight-line code.
//   * build u64 keys (conf_bits<<32 | ~idx) for 3072 cells (48/lane),
//     accumulate negative-size penalty partial
//   * radix-select the exact 100th-largest key (jax.lax.top_k semantics)
//   * compact, rank by counting, emit pred corners / conf in sorted order
//   * fix target boxes; zero maxiou_bits slice; block 0 zeros global accums
// ---------------------------------------------------------------------------
__global__ __launch_bounds__(64) void k_topk(const float* __restrict__ pred,
                                             const float* __restrict__ tgt,
                                             float* __restrict__ predc,
                                             float* __restrict__ targc,
                                             float* __restrict__ confv,
                                             unsigned int* __restrict__ maxiou_bits,
                                             double* __restrict__ negp /*[64]*/,
                                             double* __restrict__ pair_sum,
                                             unsigned int* __restrict__ done_cnt) {
    const int b = blockIdx.x;
    const int t = threadIdx.x;  // 0..63

    __shared__ unsigned long long keys[NKEY];   // 24 KB
    __shared__ unsigned int hist[256];
    __shared__ unsigned long long sel[KSEL];
    __shared__ unsigned long long tkey_sh;
    __shared__ unsigned int scnt;
    __shared__ int bdigit_sh;
    __shared__ int bk_sh;

    if (b == 0 && t == 0) { *pair_sum = 0.0; *done_cnt = 0u; }

    // ---- target box fixing (epsilon = 1.0) + maxiou init ----
    for (int n0 = t; n0 < KSEL; n0 += 64) {
        int n = b * KSEL + n0;
        const float* tb = tgt + (size_t)n * 4;
        float a0 = tb[0], a1 = tb[1], a2 = tb[2], a3 = tb[3];
        float x1 = fminf(a0, a2), y1 = fminf(a1, a3);
        float x2 = fmaxf(a0, a2), y2 = fmaxf(a1, a3);
        if (x1 == x2) x2 = x1 + 1.0f;
        if (y1 == y2) y2 = y1 + 1.0f;
        targc[n * 4 + 0] = x1; targc[n * 4 + 1] = y1;
        targc[n * 4 + 2] = x2; targc[n * 4 + 3] = y2;
        maxiou_bits[n] = 0u;
    }
    if (t == 0) scnt = 0;

    // ---- phase A: keys + negpen partial ----
    const float* pb = pred + (size_t)b * (NKEY * 5);
    double negacc = 0.0;
    for (int r = 0; r < 48; ++r) {
        int idx = t + r * 64;
        const float* pe = pb + (size_t)idx * 5;
        float w = pe[2], h = pe[3], cl = pe[4];
        negacc += (double)(fmaxf(1.0f - w, 0.0f) + fmaxf(1.0f - h, 0.0f));
        float c = sigf(cl);
        keys[idx] = ((unsigned long long)__float_as_uint(c) << 32)
                  | (unsigned long long)(0xFFFFFFFFu - (unsigned)idx);
    }
    {
        double v = negacc;
        for (int off = 32; off > 0; off >>= 1) v += __shfl_down(v, off, 64);
        if (t == 0) negp[b] = v;
    }
    __syncthreads();

    // ---- phase B: radix select (MSB-first 8-bit digits) ----
    unsigned long long prefix = 0ull;
    int plen = 0;       // matched high bits
    int k = KSEL;       // rank within prefix-matched subset
    bool done = false;
    for (int round = 0; round < 8 && !done; ++round) {
        hist[t] = 0u; hist[t + 64] = 0u; hist[t + 128] = 0u; hist[t + 192] = 0u;
        __syncthreads();
        int shift = 56 - 8 * round;
        for (int r = 0; r < 48; ++r) {
            unsigned long long key = keys[t + r * 64];
            if (plen == 0 || (key >> (64 - plen)) == (prefix >> (64 - plen))) {
                atomicAdd(&hist[(unsigned)((key >> shift) & 0xFFull)], 1u);
            }
        }
        __syncthreads();
        {   // wave-wide suffix-scan of the 256-bin histogram
            unsigned s0 = hist[4 * t + 0], s1 = hist[4 * t + 1];
            unsigned s2 = hist[4 * t + 2], s3 = hist[4 * t + 3];
            unsigned ssum = s0 + s1 + s2 + s3;
            unsigned suf = ssum;  // inclusive suffix sum across lanes
            for (int off = 1; off < 64; off <<= 1) {
                unsigned o = __shfl_down(suf, off, 64);
                if (t + off < 64) suf += o;
            }
            unsigned above = suf - ssum;  // keys with digit >= 4(t+1)
            if (above < (unsigned)k && suf >= (unsigned)k) {
                unsigned hh[4] = {s0, s1, s2, s3};
                unsigned cum = above;
                for (int q = 3; q >= 0; --q) {
                    unsigned c = hh[q];
                    if (cum + c >= (unsigned)k) { bdigit_sh = 4 * t + q; bk_sh = k - (int)cum; break; }
                    cum += c;
                }
            }
        }
        __syncthreads();
        int d = bdigit_sh;
        k = bk_sh;
        prefix |= ((unsigned long long)(unsigned)d) << shift;
        plen += 8;
        unsigned ceq = hist[d];
        if (ceq == 1u) {  // unique bucket: the 100th key is determined
            for (int r = 0; r < 48; ++r) {
                unsigned long long key = keys[t + r * 64];
                if ((key >> (64 - plen)) == (prefix >> (64 - plen))) tkey_sh = key;
            }
            done = true;  // uniform
        }
        __syncthreads();
    }
    // round 7 examines the full key (all keys unique) => tkey_sh always set
    unsigned long long T = tkey_sh;

    // ---- phase C: compact + rank + emit ----
    for (int r = 0; r < 48; ++r) {
        unsigned long long key = keys[t + r * 64];
        if (key >= T) {
            unsigned pos = atomicAdd(&scnt, 1u);  // exactly 100 total
            sel[pos] = key;
        }
    }
    __syncthreads();
    for (int n0 = t; n0 < KSEL; n0 += 64) {
        unsigned long long key = sel[n0];
        int rank = 0;
        for (int p = 0; p < KSEL; ++p) rank += (sel[p] > key) ? 1 : 0;
        unsigned idx = 0xFFFFFFFFu - (unsigned)(key & 0xFFFFFFFFull);
        float conf = __uint_as_float((unsigned)(key >> 32));
        int n = b * KSEL + rank;
        confv[n] = conf;
        const float* pe = pb + (size_t)idx * 5;
        int w = idx & 31, h = (idx >> 5) & 31;  // flat = a*1024 + h*32 + w
        float x  = (sigf(pe[0]) + (float)w) * 32.0f;
        float y  = (sigf(pe[1]) + (float)h) * 32.0f;
        float bw = expf(pe[2]) * 32.0f;
        float bh = expf(pe[3]) * 32.0f;
        predc[n * 4 + 0] = x - bw * 0.5f;
        predc[n * 4 + 1] = y - bh * 0.5f;
        predc[n * 4 + 2] = x + bw * 0.5f;
        predc[n * 4 + 3] = y + bh * 0.5f;
    }
}

// ---------------------------------------------------------------------------
// k_maxiou: grid (25, 64). block (x, y): targets j in [x*256, x*256+256),
// preds i in [y*100, y*100+100) staged in LDS (boxes + precomputed areas);
// atomicMax (float-as-uint, IoU >= 0). iou via v_rcp_f32: union > 0 strictly
// here (pred areas are exp-products > 0; target boxes epsilon-fixed), ~1 ulp.
// blockIdx.y == 0 additionally computes paired DIoU and the smooth-L1 partial.
// ---------------------------------------------------------------------------
__global__ __launch_bounds__(256) void k_maxiou(const float* __restrict__ predc,
                                                const float* __restrict__ targc,
                                                unsigned int* __restrict__ maxiou_bits,
                                                float* __restrict__ diouv,
                                                double* __restrict__ sl1p /*[25]*/) {
    __shared__ float4 pl[PCHUNK];
    __shared__ float pa_sh[PCHUNK];
    int t = threadIdx.x;
    int j = blockIdx.x * 256 + t;
    const float4* pc4 = (const float4*)predc;
    int i0 = blockIdx.y * PCHUNK;
    if (t < PCHUNK) {
        float4 p = pc4[i0 + t];
        pl[t] = p;
        pa_sh[t] = (p.z - p.x) * (p.w - p.y);
    }
    float4 tj = ((const float4*)targc)[j];
    float ta = (tj.z - tj.x) * (tj.w - tj.y);
    __syncthreads();
    float m0 = 0.0f, m1 = 0.0f;
    #pragma unroll 2
    for (int i = 0; i < PCHUNK; i += 2) {
        float4 p = pl[i];
        float w0 = fmaxf(fminf(p.z, tj.z) - fmaxf(p.x, tj.x), 0.0f);
        float h0 = fmaxf(fminf(p.w, tj.w) - fmaxf(p.y, tj.y), 0.0f);
        float in0 = w0 * h0;
        float iou0 = in0 * __builtin_amdgcn_rcpf(pa_sh[i] + ta - in0);
        m0 = fmaxf(m0, iou0);
        float4 q = pl[i + 1];
        float w1 = fmaxf(fminf(q.z, tj.z) - fmaxf(q.x, tj.x), 0.0f);
        float h1 = fmaxf(fminf(q.w, tj.w) - fmaxf(q.y, tj.y), 0.0f);
        float in1 = w1 * h1;
        float iou1 = in1 * __builtin_amdgcn_rcpf(pa_sh[i + 1] + ta - in1);
        m1 = fmaxf(m1, iou1);
    }
    m0 = fmaxf(m0, m1);
    atomicMax(&maxiou_bits[j], __float_as_uint(m0));

    if (blockIdx.y == 0) {
        float4 p = pc4[j];  // paired pred for target j
        float pa = fmaxf(p.z - p.x, 0.f) * fmaxf(p.w - p.y, 0.f);
        float ta2 = fmaxf(tj.z - tj.x, 0.f) * fmaxf(tj.w - tj.y, 0.f);
        float ix1 = fmaxf(p.x, tj.x), iy1 = fmaxf(p.y, tj.y);
        float ix2 = fminf(p.z, tj.z), iy2 = fminf(p.w, tj.w);
        float inter = fmaxf(ix2 - ix1, 0.f) * fmaxf(iy2 - iy1, 0.f);
        float iou = inter / (pa + ta2 - inter + 1e-7f);
        float pcx = (p.x + p.z) * 0.5f, pcy = (p.y + p.w) * 0.5f;
        float tcx = (tj.x + tj.z) * 0.5f, tcy = (tj.y + tj.w) * 0.5f;
        float cd = (pcx - tcx) * (pcx - tcx) + (pcy - tcy) * (pcy - tcy);
        float ex1 = fminf(p.x, tj.x), ey1 = fminf(p.y, tj.y);
        float ex2 = fmaxf(p.z, tj.z), ey2 = fmaxf(p.w, tj.w);
        float dg = (ex2 - ex1) * (ex2 - ex1) + (ey2 - ey1) * (ey2 - ey1);
        diouv[j] = 1.0f - (iou - cd / (dg + 1e-7f));
        double s = 0.0;
        {
            float d0 = p.x - tj.x, d1 = p.y - tj.y, d2 = p.z - tj.z, d3 = p.w - tj.w;
            float a0 = fabsf(d0), a1 = fabsf(d1), a2 = fabsf(d2), a3 = fabsf(d3);
            s += (double)(a0 < 1.f ? 0.5f * d0 * d0 : a0 - 0.5f);
            s += (double)(a1 < 1.f ? 0.5f * d1 * d1 : a1 - 0.5f);
            s += (double)(a2 < 1.f ? 0.5f * d2 * d2 : a2 - 0.5f);
            s += (double)(a3 < 1.f ? 0.5f * d3 * d3 : a3 - 0.5f);
        }
        double v = block_reduce_sum(s);
        if (t == 0) sl1p[blockIdx.x] = v;
    }
}

// ---------------------------------------------------------------------------
// k_pair: sum over the [N,N] broadcast of good - bad. grid (25 j, 25 i).
// (1-y)^2 precomputed in LDS; raw v_sqrt_f32 (~1 ulp vs 0.28 threshold).
// Device-scope atomicAdd into pair_sum; the LAST block (done_cnt) finalizes
// the scalar output (replaces the separate k_final launch).
// ---------------------------------------------------------------------------
__global__ __launch_bounds__(256) void k_pair(const unsigned int* __restrict__ maxiou_bits,
                                              const float* __restrict__ diouv,
                                              const float* __restrict__ confv,
                                              const double* __restrict__ sl1p,
                                              const double* __restrict__ negp,
                                              double* __restrict__ pair_sum,
                                              unsigned int* __restrict__ done_cnt,
                                              float* __restrict__ out) {
    __shared__ float oy2s[256];
    __shared__ float sl1_sh;
    int t = threadIdx.x;
    int j = blockIdx.x * 256 + t;
    if (t == 0) {
        double s = 0.0;
        for (int i = 0; i < 25; ++i) s += sl1p[i];
        sl1_sh = (float)(s / 25600.0 / 512.0);
    }
    {
        float oy = 1.0f - confv[blockIdx.y * 256 + t];
        oy2s[t] = oy * oy;
    }
    float mj = __uint_as_float(maxiou_bits[j]);
    float dj = diouv[j];
    __syncthreads();
    float xj = (1.0f - mj) * 2.0f + dj + sl1_sh;
    float a2 = xj * xj;
    float bb = 3.5f - xj;
    float b2 = bb * bb;
    float acc0 = 0.0f, acc1 = 0.0f;
    #pragma unroll 4
    for (int i = 0; i < 256; i += 2) {
        float o0 = oy2s[i], o1 = oy2s[i + 1];
        acc0 += 2.0f * __builtin_amdgcn_sqrtf(a2 + o0)
              - 1.5f * __builtin_amdgcn_sqrtf(b2 + o0);
        acc1 += 2.0f * __builtin_amdgcn_sqrtf(a2 + o1)
              - 1.5f * __builtin_amdgcn_sqrtf(b2 + o1);
    }
    double v = block_reduce_sum((double)(acc0 + acc1));
    if (t == 0) {
        atomicAdd(pair_sum, v);
        __threadfence();
        unsigned prev = atomicAdd(done_cnt, 1u);
        if (prev == 624u) {  // last block: finalize
            double ps = atomicAdd(pair_sum, 0.0);  // coherent read
            double ns = 0.0;
            for (int i = 0; i < 64; ++i) ns += negp[i];
            double mean_pair = ps / 40960000.0;                    // 6400*6400
            float losses = fmaxf((float)mean_pair + 5.25f, 0.0f);  // + 3.5*1.5
            float neg = (float)(ns / 196608.0);
            out[0] = losses + neg;
        }
    }
}

// ---------------- launch ----------------

extern "C" void kernel_launch(void* const* d_in, const int* in_sizes, int n_in,
                              void* d_out, int out_size, void* d_ws, size_t ws_size,
                              hipStream_t stream) {
    const float* pred = (const float*)d_in[0];   // [64,3,32,32,5]
    const float* tgt  = (const float*)d_in[1];   // [64,100,4]
    float* out = (float*)d_out;

    char* ws = (char*)d_ws;
    double* negp     = (double*)ws;          // 64 doubles
    double* sl1p     = negp + 64;            // 25 (padded to 32)
    double* pair_sum = negp + 96;            // 1 double
    unsigned int* done_cnt = (unsigned int*)(negp + 97);  // 1 u32 (8B slot)
    float* fbase  = (float*)(ws + 6400);     // 16B-aligned float region
    float* predc  = fbase;                   // 25600 floats
    float* targc  = fbase + 25600;           // 25600
    float* confv  = fbase + 51200;           // 6400
    float* diouv  = fbase + 57600;           // 6400
    unsigned int* maxiou_bits = (unsigned int*)(fbase + 64000);  // 6400

    k_topk<<<64, 64, 0, stream>>>(pred, tgt, predc, targc, confv, maxiou_bits,
                                  negp, pair_sum, done_cnt);
    k_maxiou<<<dim3(25, 64), 256, 0, stream>>>(predc, targc, maxiou_bits, diouv, sl1p);
    k_pair<<<dim3(25, 25), 256, 0, stream>>>(maxiou_bits, diouv, confv, sl1p,
                                             negp, pair_sum, done_cnt, out);
}

// Round 5
// 112.506 us; speedup vs baseline: 1.1578x; 1.1578x over previous
//
#include <hip/hip_runtime.h>
#include <cmath>

#define NKEY 3072
#define KSEL 100
#define PCHUNK 200   // preds per k_maxiou block; grid.y = 6400/PCHUNK = 32

static __device__ __forceinline__ float sigf(float v) {
    return 1.0f / (1.0f + expf(-v));
}

// Block (256 threads) sum-reduction in double. Valid result on thread 0.
// Leading barrier makes back-to-back calls safe.
static __device__ double block_reduce_sum(double v) {
    __shared__ double sh[4];
    __syncthreads();
    for (int off = 32; off > 0; off >>= 1) v += __shfl_down(v, off, 64);
    int lane = threadIdx.x & 63, wid = threadIdx.x >> 6;
    if (lane == 0) sh[wid] = v;
    __syncthreads();
    v = (threadIdx.x < 4) ? sh[threadIdx.x] : 0.0;
    if (wid == 0) {
        v += __shfl_down(v, 2, 64);
        v += __shfl_down(v, 1, 64);
    }
    return v;
}

// ---------------------------------------------------------------------------
// k_topk: 1024 threads (16 waves) per batch, 64 blocks. Wide blocks minimize
// per-lane serial work (3 keys/lane per phase step); barrier count stays ~12
// (radix resolves in ~2-3 rounds: sigmoid conf bits share exponent bytes).
//   * build u64 keys (conf_bits<<32 | ~idx) for 3072 cells, accumulate
//     negative-size penalty partial
//   * radix-select the exact 100th-largest key (jax.lax.top_k semantics:
//     descending value, ties -> lower index; key packing encodes this)
//   * compact, rank by counting, emit pred corners / conf in sorted order
//   * fix target boxes; zero maxiou_bits slice; block 0 zeros global accums
// ---------------------------------------------------------------------------
__global__ __launch_bounds__(1024) void k_topk(const float* __restrict__ pred,
                                               const float* __restrict__ tgt,
                                               float* __restrict__ predc,
                                               float* __restrict__ targc,
                                               float* __restrict__ confv,
                                               unsigned int* __restrict__ maxiou_bits,
                                               double* __restrict__ negp /*[64]*/,
                                               double* __restrict__ pair_sum,
                                               unsigned int* __restrict__ done_cnt) {
    const int b = blockIdx.x;
    const int t = threadIdx.x;  // 0..1023

    __shared__ unsigned long long keys[NKEY];   // 24 KB
    __shared__ unsigned int hist[256];
    __shared__ unsigned long long sel[KSEL];
    __shared__ unsigned long long tkey_sh;
    __shared__ unsigned int scnt;
    __shared__ int bdigit_sh;
    __shared__ int bk_sh;
    __shared__ double swave[16];

    if (b == 0 && t == 0) { *pair_sum = 0.0; *done_cnt = 0u; }

    // ---- target box fixing (epsilon = 1.0) + maxiou init ----
    if (t < KSEL) {
        int n = b * KSEL + t;
        const float* tb = tgt + (size_t)n * 4;
        float a0 = tb[0], a1 = tb[1], a2 = tb[2], a3 = tb[3];
        float x1 = fminf(a0, a2), y1 = fminf(a1, a3);
        float x2 = fmaxf(a0, a2), y2 = fmaxf(a1, a3);
        if (x1 == x2) x2 = x1 + 1.0f;
        if (y1 == y2) y2 = y1 + 1.0f;
        targc[n * 4 + 0] = x1; targc[n * 4 + 1] = y1;
        targc[n * 4 + 2] = x2; targc[n * 4 + 3] = y2;
        maxiou_bits[n] = 0u;
    }
    if (t == 0) scnt = 0;

    // ---- phase A: keys + negpen partial ----
    const float* pb = pred + (size_t)b * (NKEY * 5);
    float negacc = 0.0f;
    #pragma unroll
    for (int r = 0; r < 3; ++r) {
        int idx = t + r * 1024;
        const float* pe = pb + (size_t)idx * 5;
        float w = pe[2], h = pe[3], cl = pe[4];
        negacc += fmaxf(1.0f - w, 0.0f) + fmaxf(1.0f - h, 0.0f);
        float c = sigf(cl);
        keys[idx] = ((unsigned long long)__float_as_uint(c) << 32)
                  | (unsigned long long)(0xFFFFFFFFu - (unsigned)idx);
    }
    {   // 16-wave block reduction of negacc
        double v = (double)negacc;
        for (int off = 32; off > 0; off >>= 1) v += __shfl_down(v, off, 64);
        int lane = t & 63, wid = t >> 6;
        if (lane == 0) swave[wid] = v;
        __syncthreads();  // also makes keys + scnt visible
        if (t < 64) {
            v = (t < 16) ? swave[t] : 0.0;
            for (int off = 8; off > 0; off >>= 1) v += __shfl_down(v, off, 64);
            if (t == 0) negp[b] = v;
        }
    }

    // ---- phase B: radix select (MSB-first 8-bit digits) ----
    unsigned long long prefix = 0ull;
    int plen = 0;       // matched high bits
    int k = KSEL;       // rank within prefix-matched subset
    bool done = false;
    for (int round = 0; round < 8 && !done; ++round) {
        if (t < 256) hist[t] = 0u;
        __syncthreads();
        int shift = 56 - 8 * round;
        #pragma unroll
        for (int r = 0; r < 3; ++r) {
            unsigned long long key = keys[t + r * 1024];
            if (plen == 0 || (key >> (64 - plen)) == (prefix >> (64 - plen))) {
                atomicAdd(&hist[(unsigned)((key >> shift) & 0xFFull)], 1u);
            }
        }
        __syncthreads();
        if (t < 64) {  // wave 0: suffix-scan the 256-bin histogram
            unsigned s0 = hist[4 * t + 0], s1 = hist[4 * t + 1];
            unsigned s2 = hist[4 * t + 2], s3 = hist[4 * t + 3];
            unsigned ssum = s0 + s1 + s2 + s3;
            unsigned suf = ssum;  // inclusive suffix sum across lanes
            for (int off = 1; off < 64; off <<= 1) {
                unsigned o = __shfl_down(suf, off, 64);
                if (t + off < 64) suf += o;
            }
            unsigned above = suf - ssum;  // keys with digit >= 4(t+1)
            if (above < (unsigned)k && suf >= (unsigned)k) {
                unsigned hh[4] = {s0, s1, s2, s3};
                unsigned cum = above;
                for (int q = 3; q >= 0; --q) {
                    unsigned c = hh[q];
                    if (cum + c >= (unsigned)k) { bdigit_sh = 4 * t + q; bk_sh = k - (int)cum; break; }
                    cum += c;
                }
            }
        }
        __syncthreads();
        int d = bdigit_sh;
        k = bk_sh;
        prefix |= ((unsigned long long)(unsigned)d) << shift;
        plen += 8;
        unsigned ceq = hist[d];
        if (ceq == 1u) {  // unique bucket: the 100th key is determined
            #pragma unroll
            for (int r = 0; r < 3; ++r) {
                unsigned long long key = keys[t + r * 1024];
                if ((key >> (64 - plen)) == (prefix >> (64 - plen))) tkey_sh = key;
            }
            done = true;  // uniform (ceq is uniform)
        }
        __syncthreads();
    }
    // round 7 examines the full key (all keys unique) => tkey_sh always set
    unsigned long long T = tkey_sh;

    // ---- phase C: compact + rank + emit ----
    #pragma unroll
    for (int r = 0; r < 3; ++r) {
        unsigned long long key = keys[t + r * 1024];
        if (key >= T) {
            unsigned pos = atomicAdd(&scnt, 1u);  // exactly 100 total
            sel[pos] = key;
        }
    }
    __syncthreads();
    if (t < KSEL) {
        unsigned long long key = sel[t];
        int rank = 0;
        for (int p = 0; p < KSEL; ++p) rank += (sel[p] > key) ? 1 : 0;
        unsigned idx = 0xFFFFFFFFu - (unsigned)(key & 0xFFFFFFFFull);
        float conf = __uint_as_float((unsigned)(key >> 32));
        int n = b * KSEL + rank;
        confv[n] = conf;
        const float* pe = pb + (size_t)idx * 5;
        int w = idx & 31, h = (idx >> 5) & 31;  // flat = a*1024 + h*32 + w
        float x  = (sigf(pe[0]) + (float)w) * 32.0f;
        float y  = (sigf(pe[1]) + (float)h) * 32.0f;
        float bw = expf(pe[2]) * 32.0f;
        float bh = expf(pe[3]) * 32.0f;
        predc[n * 4 + 0] = x - bw * 0.5f;
        predc[n * 4 + 1] = y - bh * 0.5f;
        predc[n * 4 + 2] = x + bw * 0.5f;
        predc[n * 4 + 3] = y + bh * 0.5f;
    }
}

// ---------------------------------------------------------------------------
// k_maxiou: grid (25, 32). block (x, y): targets j in [x*256, x*256+256),
// preds i in [y*200, y*200+200) staged in LDS (boxes + precomputed areas);
// atomicMax (float-as-uint, IoU >= 0). iou via v_rcp_f32: union > 0 strictly
// here (pred areas are exp-products > 0; target boxes epsilon-fixed), ~1 ulp.
// blockIdx.y == 0 additionally computes paired DIoU and the smooth-L1 partial.
// ---------------------------------------------------------------------------
__global__ __launch_bounds__(256) void k_maxiou(const float* __restrict__ predc,
                                                const float* __restrict__ targc,
                                                unsigned int* __restrict__ maxiou_bits,
                                                float* __restrict__ diouv,
                                                double* __restrict__ sl1p /*[25]*/) {
    __shared__ float4 pl[PCHUNK];
    __shared__ float pa_sh[PCHUNK];
    int t = threadIdx.x;
    int j = blockIdx.x * 256 + t;
    const float4* pc4 = (const float4*)predc;
    int i0 = blockIdx.y * PCHUNK;
    for (int i = t; i < PCHUNK; i += 256) {
        float4 p = pc4[i0 + i];
        pl[i] = p;
        pa_sh[i] = (p.z - p.x) * (p.w - p.y);
    }
    float4 tj = ((const float4*)targc)[j];
    float ta = (tj.z - tj.x) * (tj.w - tj.y);
    __syncthreads();
    float m0 = 0.0f, m1 = 0.0f;
    #pragma unroll 2
    for (int i = 0; i < PCHUNK; i += 2) {
        float4 p = pl[i];
        float w0 = fmaxf(fminf(p.z, tj.z) - fmaxf(p.x, tj.x), 0.0f);
        float h0 = fmaxf(fminf(p.w, tj.w) - fmaxf(p.y, tj.y), 0.0f);
        float in0 = w0 * h0;
        float iou0 = in0 * __builtin_amdgcn_rcpf(pa_sh[i] + ta - in0);
        m0 = fmaxf(m0, iou0);
        float4 q = pl[i + 1];
        float w1 = fmaxf(fminf(q.z, tj.z) - fmaxf(q.x, tj.x), 0.0f);
        float h1 = fmaxf(fminf(q.w, tj.w) - fmaxf(q.y, tj.y), 0.0f);
        float in1 = w1 * h1;
        float iou1 = in1 * __builtin_amdgcn_rcpf(pa_sh[i + 1] + ta - in1);
        m1 = fmaxf(m1, iou1);
    }
    m0 = fmaxf(m0, m1);
    atomicMax(&maxiou_bits[j], __float_as_uint(m0));

    if (blockIdx.y == 0) {
        float4 p = pc4[j];  // paired pred for target j
        float pa = fmaxf(p.z - p.x, 0.f) * fmaxf(p.w - p.y, 0.f);
        float ta2 = fmaxf(tj.z - tj.x, 0.f) * fmaxf(tj.w - tj.y, 0.f);
        float ix1 = fmaxf(p.x, tj.x), iy1 = fmaxf(p.y, tj.y);
        float ix2 = fminf(p.z, tj.z), iy2 = fminf(p.w, tj.w);
        float inter = fmaxf(ix2 - ix1, 0.f) * fmaxf(iy2 - iy1, 0.f);
        float iou = inter / (pa + ta2 - inter + 1e-7f);
        float pcx = (p.x + p.z) * 0.5f, pcy = (p.y + p.w) * 0.5f;
        float tcx = (tj.x + tj.z) * 0.5f, tcy = (tj.y + tj.w) * 0.5f;
        float cd = (pcx - tcx) * (pcx - tcx) + (pcy - tcy) * (pcy - tcy);
        float ex1 = fminf(p.x, tj.x), ey1 = fminf(p.y, tj.y);
        float ex2 = fmaxf(p.z, tj.z), ey2 = fmaxf(p.w, tj.w);
        float dg = (ex2 - ex1) * (ex2 - ex1) + (ey2 - ey1) * (ey2 - ey1);
        diouv[j] = 1.0f - (iou - cd / (dg + 1e-7f));
        double s = 0.0;
        {
            float d0 = p.x - tj.x, d1 = p.y - tj.y, d2 = p.z - tj.z, d3 = p.w - tj.w;
            float a0 = fabsf(d0), a1 = fabsf(d1), a2 = fabsf(d2), a3 = fabsf(d3);
            s += (double)(a0 < 1.f ? 0.5f * d0 * d0 : a0 - 0.5f);
            s += (double)(a1 < 1.f ? 0.5f * d1 * d1 : a1 - 0.5f);
            s += (double)(a2 < 1.f ? 0.5f * d2 * d2 : a2 - 0.5f);
            s += (double)(a3 < 1.f ? 0.5f * d3 * d3 : a3 - 0.5f);
        }
        double v = block_reduce_sum(s);
        if (t == 0) sl1p[blockIdx.x] = v;
    }
}

// ---------------------------------------------------------------------------
// k_pair: sum over the [N,N] broadcast of good - bad. grid (25 j, 25 i).
// (1-y)^2 precomputed in LDS; raw v_sqrt_f32 (~1 ulp vs 0.28 threshold).
// Device-scope atomicAdd into pair_sum; the LAST block (done_cnt) finalizes
// the scalar output (replaces a separate k_final launch).
// ---------------------------------------------------------------------------
__global__ __launch_bounds__(256) void k_pair(const unsigned int* __restrict__ maxiou_bits,
                                              const float* __restrict__ diouv,
                                              const float* __restrict__ confv,
                                              const double* __restrict__ sl1p,
                                              const double* __restrict__ negp,
                                              double* __restrict__ pair_sum,
                                              unsigned int* __restrict__ done_cnt,
                                              float* __restrict__ out) {
    __shared__ float oy2s[256];
    __shared__ float sl1_sh;
    int t = threadIdx.x;
    int j = blockIdx.x * 256 + t;
    if (t == 0) {
        double s = 0.0;
        for (int i = 0; i < 25; ++i) s += sl1p[i];
        sl1_sh = (float)(s / 25600.0 / 512.0);
    }
    {
        float oy = 1.0f - confv[blockIdx.y * 256 + t];
        oy2s[t] = oy * oy;
    }
    float mj = __uint_as_float(maxiou_bits[j]);
    float dj = diouv[j];
    __syncthreads();
    float xj = (1.0f - mj) * 2.0f + dj + sl1_sh;
    float a2 = xj * xj;
    float bb = 3.5f - xj;
    float b2 = bb * bb;
    float acc0 = 0.0f, acc1 = 0.0f;
    #pragma unroll 4
    for (int i = 0; i < 256; i += 2) {
        float o0 = oy2s[i], o1 = oy2s[i + 1];
        acc0 += 2.0f * __builtin_amdgcn_sqrtf(a2 + o0)
              - 1.5f * __builtin_amdgcn_sqrtf(b2 + o0);
        acc1 += 2.0f * __builtin_amdgcn_sqrtf(a2 + o1)
              - 1.5f * __builtin_amdgcn_sqrtf(b2 + o1);
    }
    double v = block_reduce_sum((double)(acc0 + acc1));
    if (t == 0) {
        atomicAdd(pair_sum, v);
        __threadfence();
        unsigned prev = atomicAdd(done_cnt, 1u);
        if (prev == 624u) {  // last block: finalize
            double ps = atomicAdd(pair_sum, 0.0);  // coherent read
            double ns = 0.0;
            for (int i = 0; i < 64; ++i) ns += negp[i];
            double mean_pair = ps / 40960000.0;                    // 6400*6400
            float losses = fmaxf((float)mean_pair + 5.25f, 0.0f);  // + 3.5*1.5
            float neg = (float)(ns / 196608.0);
            out[0] = losses + neg;
        }
    }
}

// ---------------- launch ----------------

extern "C" void kernel_launch(void* const* d_in, const int* in_sizes, int n_in,
                              void* d_out, int out_size, void* d_ws, size_t ws_size,
                              hipStream_t stream) {
    const float* pred = (const float*)d_in[0];   // [64,3,32,32,5]
    const float* tgt  = (const float*)d_in[1];   // [64,100,4]
    float* out = (float*)d_out;

    char* ws = (char*)d_ws;
    double* negp     = (double*)ws;          // 64 doubles
    double* sl1p     = negp + 64;            // 25 (padded to 32)
    double* pair_sum = negp + 96;            // 1 double
    unsigned int* done_cnt = (unsigned int*)(negp + 97);  // 1 u32 (8B slot)
    float* fbase  = (float*)(ws + 6400);     // 16B-aligned float region
    float* predc  = fbase;                   // 25600 floats
    float* targc  = fbase + 25600;           // 25600
    float* confv  = fbase + 51200;           // 6400
    float* diouv  = fbase + 57600;           // 6400
    unsigned int* maxiou_bits = (unsigned int*)(fbase + 64000);  // 6400

    k_topk<<<64, 1024, 0, stream>>>(pred, tgt, predc, targc, confv, maxiou_bits,
                                    negp, pair_sum, done_cnt);
    k_maxiou<<<dim3(25, 32), 256, 0, stream>>>(predc, targc, maxiou_bits, diouv, sl1p);
    k_pair<<<dim3(25, 25), 256, 0, stream>>>(maxiou_bits, diouv, confv, sl1p,
                                             negp, pair_sum, done_cnt, out);
}